// Round 2
// baseline (279.742 us; speedup 1.0000x reference)
//
#include <hip/hip_runtime.h>
#include <hip/hip_bf16.h>

// ---------------------------------------------------------------------------
// DeformableSpatialEncoder on MI355X (gfx950)
//
// Pipeline (N=64 images, Lq=196 tokens, D=768, heads=4, Dh=192, points=4):
//   1. stage:  [merged]
//        blocks [0,42):    weight-fold GEMM  Wc[896,768] = Wcat @ We  (bf16 MFMA,
//                          in-register f32->bf16 cast staging). Dispatched FIRST
//                          so it overlaps the memory-bound im2col stream.
//        blocks [42,46):   bcat2[o] = Wcat[o,:]·embed_b + bcat[o]   (f32 dots)
//        blocks [46,94):   zero core
//        blocks [94,9502): im2col x -> A bf16 [12544,768] (coalesced writes)
//      Folding identity: feat is ONLY consumed by the cat-GEMM, so
//        cat = (A@We^T+be)@Wcat^T+bcat = A@(Wcat·We)^T + (Wcat·be + bcat)
//      -> the former gemm1 (14.8 GF) is eliminated.
//   2. gemm2:  mixed epilogue: value -> Vbuf bf16 [12544,768],
//              off/aw logits -> OA f32 [12544,64]  (A @ Wc^T + bcat2)
//   3. deform: core_mean[64,768] += mean_lq( softmax(aw) * bilinear(value) )
//   4. pooled = core_mean @ outp_w^T + outp_b   (mean commutes with linear)
//   5. final  = pooled @ proj_w^T + proj_b -> d_out
//      4/5 use small_linear4: 4 images/block share one W read (LDS-staged
//      inputs, broadcast), cutting W L2 traffic 4x vs one-output-per-thread.
// ---------------------------------------------------------------------------

using bf16 = __bf16;
typedef bf16  bf16x8 __attribute__((ext_vector_type(8)));
typedef float f32x4  __attribute__((ext_vector_type(4)));

#define N_IMG   64
#define LQ      196
#define DM      768
#define NH      4
#define DH      192
#define M_ROWS  (N_IMG * LQ)        // 12544
#define NCAT    896                 // 768 value + 32 off + 16 aw + 80 pad

// stage grid layout
#define B_WGEMM   0                 // 42 blocks: 7 (o-tiles) x 6 (k-tiles)
#define B_BCAT    42                // 4 blocks
#define B_ZERO    46                // 48 blocks
#define B_IM2COL  94                // 9408 blocks
#define STAGE_GRID (B_IM2COL + 9408)

// ---- workspace layout (bytes, all 256-aligned) ----
#define OFF_A     ((size_t)0)                      // 12544*768*2 = 19267584
#define OFF_WC    (OFF_A    + 19267584)            // 896*768*2   = 1376256
#define OFF_BCAT  (OFF_WC   + 1376256)             // 4096
#define OFF_VBUF  (OFF_BCAT + 4096)                // 12544*768*2 = 19267584
#define OFF_OA    (OFF_VBUF + 19267584)            // 12544*64*4  = 3211264
#define OFF_CORE  (OFF_OA   + 3211264)             // 196608
#define OFF_POOL  (OFF_CORE + 196608)              // 196608

__device__ __forceinline__ void gload_lds16(const bf16* g, bf16* l) {
#if __has_builtin(__builtin_amdgcn_global_load_lds)
  __builtin_amdgcn_global_load_lds(
      (const __attribute__((address_space(1))) void*)g,
      (__attribute__((address_space(3))) void*)l, 16, 0, 0);
#else
  *(bf16x8*)l = *(const bf16x8*)g;
#endif
}

// ---------------------------------------------------------------------------
// stage kernel (see layout above)
// ---------------------------------------------------------------------------
__global__ void stage_kernel(const float* __restrict__ x,
                             const float* __restrict__ embed_w,
                             const float* __restrict__ embed_b,
                             const float* __restrict__ value_w,
                             const float* __restrict__ off_w,
                             const float* __restrict__ aw_w,
                             const float* __restrict__ value_b,
                             const float* __restrict__ off_b,
                             const float* __restrict__ aw_b,
                             bf16* __restrict__ A,
                             bf16* __restrict__ Wc,
                             float* __restrict__ bcat2,
                             float* __restrict__ core) {
  __shared__ bf16 As[128 * 64];
  __shared__ bf16 Bs[128 * 64];
  const int bid = blockIdx.x;
  const int tid = threadIdx.x;

  if (bid >= B_IM2COL) {                 // ---- im2col ----
    const int t   = (bid - B_IM2COL) * 256 + tid;  // < 12544*192 exactly
    const int row = t / 192;
    const int j   = t - row * 192;
    const int k   = j * 4;               // k = c*256 + p*16 + q, q%4==0
    const int c   = k >> 8;
    const int r   = k & 255;
    const int p   = r >> 4;
    const int q   = r & 15;
    const int n   = row / 196;
    const int lq  = row - n * 196;
    const int h   = lq / 14;
    const int w   = lq - h * 14;
    const float4 v = *(const float4*)(x +
        ((((size_t)n * 3 + c) * 224) + h * 16 + p) * 224 + w * 16 + q);
    bf16* dst = A + (size_t)row * DM + k;
    dst[0] = (bf16)v.x; dst[1] = (bf16)v.y; dst[2] = (bf16)v.z; dst[3] = (bf16)v.w;
    return;
  }

  if (bid < B_BCAT) {                    // ---- weight-fold GEMM ----
    // Wc[o,k] = sum_f Wcat[o,f] * embed_w[f,k];  Wcat rows: value_w/off_w/aw_w
    const int mT = bid / 6;              // 0..6   o-tile
    const int nT = bid - mT * 6;         // 0..5   k-tile
    const int oBase = mT * 128;
    const int nBase = nT * 128;
    const int wave = tid >> 6;
    const int lane = tid & 63;
    const int quad = lane >> 4;
    const int r16  = lane & 15;
    const int wm = wave & 1;
    const int wn = wave >> 1;
    const int srow = wave * 32 + (lane >> 3);
    const int scol = (lane & 7) * 8;

    const float* asrc[4];
#pragma unroll
    for (int i = 0; i < 4; ++i) {
      const int o = oBase + srow + i * 8;
      asrc[i] = (o < 768) ? value_w + (size_t)o * DM
              : (o < 800) ? off_w + (size_t)(o - 768) * DM
              : (o < 816) ? aw_w + (size_t)(o - 800) * DM : nullptr;
    }

    const f32x4 zero = {0.f, 0.f, 0.f, 0.f};
    f32x4 acc[4][4];
#pragma unroll
    for (int mi = 0; mi < 4; ++mi)
#pragma unroll
      for (int ni = 0; ni < 4; ++ni) acc[mi][ni] = zero;

    for (int kt = 0; kt < DM; kt += 64) {
#pragma unroll
      for (int i = 0; i < 4; ++i) {
        const int r = srow + i * 8;
        bf16x8 av;
        if (asrc[i]) {
          const float4 f0 = *(const float4*)(asrc[i] + kt + scol);
          const float4 f1 = *(const float4*)(asrc[i] + kt + scol + 4);
          av[0] = (bf16)f0.x; av[1] = (bf16)f0.y;
          av[2] = (bf16)f0.z; av[3] = (bf16)f0.w;
          av[4] = (bf16)f1.x; av[5] = (bf16)f1.y;
          av[6] = (bf16)f1.z; av[7] = (bf16)f1.w;
        } else {
#pragma unroll
          for (int jj = 0; jj < 8; ++jj) av[jj] = (bf16)0.f;
        }
        *(bf16x8*)&As[r * 64 + scol] = av;
        // B[n,f] = embed_w[f*768 + n]  (transposed read, strided; small data)
        const int n = nBase + r;
        bf16x8 bv;
#pragma unroll
        for (int jj = 0; jj < 8; ++jj)
          bv[jj] = (bf16)embed_w[(size_t)(kt + scol + jj) * DM + n];
        *(bf16x8*)&Bs[r * 64 + scol] = bv;
      }
      __syncthreads();
#pragma unroll
      for (int kk = 0; kk < 64; kk += 32) {
        bf16x8 af[4], bfr[4];
#pragma unroll
        for (int mi = 0; mi < 4; ++mi)
          af[mi] = *(const bf16x8*)&As[(wm * 64 + mi * 16 + r16) * 64 + kk + quad * 8];
#pragma unroll
        for (int ni = 0; ni < 4; ++ni)
          bfr[ni] = *(const bf16x8*)&Bs[(wn * 64 + ni * 16 + r16) * 64 + kk + quad * 8];
#pragma unroll
        for (int mi = 0; mi < 4; ++mi)
#pragma unroll
          for (int ni = 0; ni < 4; ++ni)
            acc[mi][ni] = __builtin_amdgcn_mfma_f32_16x16x32_bf16(
                af[mi], bfr[ni], acc[mi][ni], 0, 0, 0);
      }
      __syncthreads();
    }
#pragma unroll
    for (int ni = 0; ni < 4; ++ni) {
      const int col = nBase + wn * 64 + ni * 16 + r16;
#pragma unroll
      for (int mi = 0; mi < 4; ++mi) {
        const int row0 = oBase + wm * 64 + mi * 16 + quad * 4;
#pragma unroll
        for (int rr = 0; rr < 4; ++rr)
          Wc[(size_t)(row0 + rr) * DM + col] = (bf16)acc[mi][ni][rr];
      }
    }
    return;
  }

  if (bid < B_ZERO) {                    // ---- bcat2 = Wcat @ embed_b + bcat ----
    const int o = (bid - B_BCAT) * 256 + tid;   // 0..1023
    if (o < NCAT) {
      float bias_o = (o < 768) ? value_b[o]
                   : (o < 800) ? off_b[o - 768]
                   : (o < 816) ? aw_b[o - 800] : 0.f;
      float acc = 0.f;
      if (o < 816) {
        const float* wr = (o < 768) ? value_w + (size_t)o * DM
                        : (o < 800) ? off_w + (size_t)(o - 768) * DM
                        : aw_w + (size_t)(o - 800) * DM;
        const float4* w4p = (const float4*)wr;
        const float4* b4p = (const float4*)embed_b;
#pragma unroll 4
        for (int k = 0; k < DM / 4; ++k) {
          const float4 wv = w4p[k], bv = b4p[k];
          acc += wv.x * bv.x + wv.y * bv.y + wv.z * bv.z + wv.w * bv.w;
        }
      }
      bcat2[o] = acc + bias_o;
    }
    return;
  }

  // ---- zero core ----  (48 blocks x 256 threads x float4 = 49152 floats)
  const int i = (bid - B_ZERO) * 256 + tid;
  f32x4 z = {0.f, 0.f, 0.f, 0.f};
  ((f32x4*)core)[i] = z;
}

// ---------------------------------------------------------------------------
// gemm2_mixed: C = A[M,K]bf16 @ B[N,K]bf16^T + bias; epilogue splits columns:
//   col <  768 -> Vbuf bf16 [M,768]
//   col <  816 -> OA   f32  [M,64]  at col-768 (0..31 off, 32..47 aw)
//   col >= 816 -> dropped (zero-pad columns)
// 128x128 tile, BK=64, 256 threads (4 waves, 2x2), mfma_f32_16x16x32_bf16.
// ---------------------------------------------------------------------------
__global__ void gemm2_mixed(const bf16* __restrict__ A, const bf16* __restrict__ B,
                            const float* __restrict__ bias,
                            bf16* __restrict__ Vb, float* __restrict__ OA,
                            int M, int N, int K) {
  __shared__ bf16 As[128 * 64];
  __shared__ bf16 Bs[128 * 64];

  const int tid  = threadIdx.x;
  const int wave = tid >> 6;
  const int lane = tid & 63;
  const int nBase = blockIdx.x * 128;
  const int mBase = blockIdx.y * 128;
  const int wm = wave & 1;
  const int wn = wave >> 1;
  const int quad = lane >> 4;
  const int r16  = lane & 15;

  const f32x4 zero = {0.f, 0.f, 0.f, 0.f};
  f32x4 acc[4][4];
#pragma unroll
  for (int mi = 0; mi < 4; ++mi)
#pragma unroll
    for (int ni = 0; ni < 4; ++ni) acc[mi][ni] = zero;

  const int srow = wave * 32 + (lane >> 3);
  const int scol = (lane & 7) * 8;
  const bf16* Ag = A + (size_t)(mBase + srow) * K + scol;
  const bf16* Bg = B + (size_t)(nBase + srow) * K + scol;
  bf16* Al = As + srow * 64 + scol;
  bf16* Bl = Bs + srow * 64 + scol;

  for (int kt = 0; kt < K; kt += 64) {
#pragma unroll
    for (int i = 0; i < 4; ++i) {
      gload_lds16(Ag + (size_t)(i * 8) * K + kt, Al + i * 8 * 64);
      gload_lds16(Bg + (size_t)(i * 8) * K + kt, Bl + i * 8 * 64);
    }
    __syncthreads();
#pragma unroll
    for (int kk = 0; kk < 64; kk += 32) {
      bf16x8 af[4], bfr[4];
#pragma unroll
      for (int mi = 0; mi < 4; ++mi)
        af[mi] = *(const bf16x8*)&As[(wm * 64 + mi * 16 + r16) * 64 + kk + quad * 8];
#pragma unroll
      for (int ni = 0; ni < 4; ++ni)
        bfr[ni] = *(const bf16x8*)&Bs[(wn * 64 + ni * 16 + r16) * 64 + kk + quad * 8];
#pragma unroll
      for (int mi = 0; mi < 4; ++mi)
#pragma unroll
        for (int ni = 0; ni < 4; ++ni)
          acc[mi][ni] = __builtin_amdgcn_mfma_f32_16x16x32_bf16(
              af[mi], bfr[ni], acc[mi][ni], 0, 0, 0);
    }
    __syncthreads();
  }

  // epilogue: C row = quad*4 + reg, col = lane&15 (m89/m91-verified layout)
#pragma unroll
  for (int ni = 0; ni < 4; ++ni) {
    const int col = nBase + wn * 64 + ni * 16 + r16;
    const float bv = bias[col];
#pragma unroll
    for (int mi = 0; mi < 4; ++mi) {
      const int row0 = mBase + wm * 64 + mi * 16 + quad * 4;
#pragma unroll
      for (int rr = 0; rr < 4; ++rr) {
        float v = acc[mi][ni][rr] + bv;
        int row = row0 + rr;
        if (col < 768) {
          Vb[(size_t)row * 768 + col] = (bf16)v;
        } else if (col < 816) {
          OA[(size_t)row * 64 + (col - 768)] = v;
        }
      }
    }
  }
}

// ---------------------------------------------------------------------------
// deform: grid (64, 49, 3), block 256.
// Phase 1 (64 threads): per (lq_i, head, point) compute 4 combined
//   softmax*bilinear*validity weights + 4 clamped token indices -> LDS.
// Phase 2 (256 threads): thread = channel; 64 unconditional bf16 gathers
//   from Vbuf, weights broadcast from LDS (waves are head-uniform).
// ---------------------------------------------------------------------------
__global__ void deform_kernel(const bf16* __restrict__ Vb,
                              const float* __restrict__ OA,
                              float* __restrict__ core) {
  __shared__ float s_w[64][4];
  __shared__ int   s_t[64][4];

  const int n   = blockIdx.x;
  const int lq0 = blockIdx.y * 4;
  const int z   = blockIdx.z;
  const int tid = threadIdx.x;

  if (tid < 64) {
    const int i = tid >> 4;          // lq within group
    const int m = (tid >> 2) & 3;    // head
    const int p = tid & 3;           // point
    const int lq = lq0 + i;
    const float* row = OA + ((size_t)n * LQ + lq) * 64;

    const float l0 = row[32 + m * 4 + 0];
    const float l1 = row[32 + m * 4 + 1];
    const float l2 = row[32 + m * 4 + 2];
    const float l3 = row[32 + m * 4 + 3];
    const float mx = fmaxf(fmaxf(l0, l1), fmaxf(l2, l3));
    const float e0 = __expf(l0 - mx), e1 = __expf(l1 - mx);
    const float e2 = __expf(l2 - mx), e3 = __expf(l3 - mx);
    const float inv = 1.f / (e0 + e1 + e2 + e3);
    const float ep[4] = {e0, e1, e2, e3};
    const float ew = ep[p] * inv;

    const int h = lq / 14, w = lq - (lq / 14) * 14;
    // px = w*14/13 + offx - 0.5  (ref linspace(0,1,14), normalizer W=14)
    const float px = (float)w * (14.f / 13.f) - 0.5f + row[(m * 4 + p) * 2 + 0];
    const float py = (float)h * (14.f / 13.f) - 0.5f + row[(m * 4 + p) * 2 + 1];
    const float fx = floorf(px), fy = floorf(py);
    const int x0 = (int)fx, y0 = (int)fy;
    const float wx1 = px - fx, wy1 = py - fy;
    const float wx0 = 1.f - wx1, wy0 = 1.f - wy1;

    const bool vx0 = (x0 >= 0) & (x0 < 14);
    const bool vx1 = (x0 >= -1) & (x0 < 13);
    const bool vy0 = (y0 >= 0) & (y0 < 14);
    const bool vy1 = (y0 >= -1) & (y0 < 13);
    const int cx0 = min(max(x0, 0), 13),      cx1 = min(max(x0 + 1, 0), 13);
    const int cy0 = min(max(y0, 0), 13) * 14, cy1 = min(max(y0 + 1, 0), 13) * 14;

    s_w[tid][0] = (vx0 & vy0) ? ew * wx0 * wy0 : 0.f;
    s_w[tid][1] = (vx1 & vy0) ? ew * wx1 * wy0 : 0.f;
    s_w[tid][2] = (vx0 & vy1) ? ew * wx0 * wy1 : 0.f;
    s_w[tid][3] = (vx1 & vy1) ? ew * wx1 * wy1 : 0.f;
    s_t[tid][0] = cy0 + cx0;
    s_t[tid][1] = cy0 + cx1;
    s_t[tid][2] = cy1 + cx0;
    s_t[tid][3] = cy1 + cx1;
  }
  __syncthreads();

  const int ch = z * 256 + tid;     // 0..767 (value column)
  const int m  = ch / DH;           // head (wave-uniform)
  const bf16* vb = Vb + (size_t)n * LQ * 768 + ch;
  float acc = 0.f;
#pragma unroll
  for (int i = 0; i < 4; ++i) {
#pragma unroll
    for (int p = 0; p < 4; ++p) {
      const int e = i * 16 + m * 4 + p;
      const float4 w4 = *(const float4*)s_w[e];
      const int4   t4 = *(const int4*)s_t[e];
      acc += w4.x * (float)vb[(size_t)t4.x * 768];
      acc += w4.y * (float)vb[(size_t)t4.y * 768];
      acc += w4.z * (float)vb[(size_t)t4.z * 768];
      acc += w4.w * (float)vb[(size_t)t4.w * 768];
    }
  }
  atomicAdd(&core[(size_t)n * DM + ch], acc * (1.f / 196.f));
}

// ---------------------------------------------------------------------------
// small_linear4: out[n][d] = sum_k in[n][k] * W[d][k] + b[d]
// 4 images per block share one coalesced W read; inputs staged in LDS and
// broadcast. Cuts W L2 traffic 4x vs one-output-per-thread.
// grid (N_IMG/4, DM/256), block 256.
// ---------------------------------------------------------------------------
__global__ void small_linear4(const float* __restrict__ in,
                              const float* __restrict__ W,
                              const float* __restrict__ b,
                              float* __restrict__ out) {
  __shared__ float s_in[4 * DM];
  const int tid = threadIdx.x;
  const int n0 = blockIdx.x * 4;
  const float4* src = (const float4*)(in + (size_t)n0 * DM);
#pragma unroll
  for (int i = 0; i < 3; ++i)            // 4*768 floats = 768 float4
    ((float4*)s_in)[tid + i * 256] = src[tid + i * 256];
  __syncthreads();

  const int d = blockIdx.y * 256 + tid;
  const float4* w4p = (const float4*)(W + (size_t)d * DM);
  const float4* s0 = (const float4*)(s_in);
  const float4* s1 = (const float4*)(s_in + DM);
  const float4* s2 = (const float4*)(s_in + 2 * DM);
  const float4* s3 = (const float4*)(s_in + 3 * DM);
  float a0 = 0.f, a1 = 0.f, a2 = 0.f, a3 = 0.f;
#pragma unroll 4
  for (int k = 0; k < DM / 4; ++k) {
    const float4 w = w4p[k];
    const float4 v0 = s0[k], v1 = s1[k], v2 = s2[k], v3 = s3[k];
    a0 += w.x * v0.x + w.y * v0.y + w.z * v0.z + w.w * v0.w;
    a1 += w.x * v1.x + w.y * v1.y + w.z * v1.z + w.w * v1.w;
    a2 += w.x * v2.x + w.y * v2.y + w.z * v2.z + w.w * v2.w;
    a3 += w.x * v3.x + w.y * v3.y + w.z * v3.z + w.w * v3.w;
  }
  const float bv = b[d];
  out[(size_t)(n0 + 0) * DM + d] = a0 + bv;
  out[(size_t)(n0 + 1) * DM + d] = a1 + bv;
  out[(size_t)(n0 + 2) * DM + d] = a2 + bv;
  out[(size_t)(n0 + 3) * DM + d] = a3 + bv;
}

// ---------------------------------------------------------------------------
extern "C" void kernel_launch(void* const* d_in, const int* in_sizes, int n_in,
                              void* d_out, int out_size, void* d_ws, size_t ws_size,
                              hipStream_t stream) {
  const float* x       = (const float*)d_in[0];
  const float* embed_w = (const float*)d_in[1];
  const float* embed_b = (const float*)d_in[2];
  const float* value_w = (const float*)d_in[3];
  const float* value_b = (const float*)d_in[4];
  const float* off_w   = (const float*)d_in[5];
  const float* off_b   = (const float*)d_in[6];
  const float* aw_w    = (const float*)d_in[7];
  const float* aw_b    = (const float*)d_in[8];
  const float* outp_w  = (const float*)d_in[9];
  const float* outp_b  = (const float*)d_in[10];
  const float* proj_w  = (const float*)d_in[11];
  const float* proj_b  = (const float*)d_in[12];
  float* out = (float*)d_out;

  char* ws = (char*)d_ws;
  bf16*  A      = (bf16*)(ws + OFF_A);
  bf16*  Wc     = (bf16*)(ws + OFF_WC);
  float* bcat2  = (float*)(ws + OFF_BCAT);
  bf16*  Vbuf   = (bf16*)(ws + OFF_VBUF);
  float* OA     = (float*)(ws + OFF_OA);
  float* core   = (float*)(ws + OFF_CORE);
  float* pooled = (float*)(ws + OFF_POOL);

  stage_kernel<<<dim3(STAGE_GRID), dim3(256), 0, stream>>>(
      x, embed_w, embed_b, value_w, off_w, aw_w, value_b, off_b, aw_b,
      A, Wc, bcat2, core);

  gemm2_mixed<<<dim3(NCAT / 128, M_ROWS / 128), dim3(256), 0, stream>>>(
      A, Wc, bcat2, Vbuf, OA, M_ROWS, NCAT, DM);

  deform_kernel<<<dim3(N_IMG, 49, 3), dim3(256), 0, stream>>>(Vbuf, OA, core);

  small_linear4<<<dim3(N_IMG / 4, 3), dim3(256), 0, stream>>>(core, outp_w, outp_b, pooled);
  small_linear4<<<dim3(N_IMG / 4, 3), dim3(256), 0, stream>>>(pooled, proj_w, proj_b, out);
}